// Round 5
// baseline (1484.818 us; speedup 1.0000x reference)
//
#include <hip/hip_runtime.h>
#include <hip/hip_bf16.h>

// GeomEncoder: B=2048, N=100 nodes, D=256, 4 dense-GAT layers.
// 512 threads (8 waves) per batch-block, 2 blocks/CU (LDS 80768B, VGPR<=128).
// g kept per-wave in registers; PV B-fragments built via ds_bpermute (no GsT tile).

typedef __attribute__((ext_vector_type(8))) short bf16x8;  // 8 bf16 = 4 VGPRs
typedef __attribute__((ext_vector_type(4))) short bf16x4;  // 8 bytes
typedef __attribute__((ext_vector_type(4))) float f32x4;
typedef __attribute__((ext_vector_type(4))) int   i32x4;

__device__ __forceinline__ float bf2f(unsigned short u) {
    return __uint_as_float(((unsigned)u) << 16);
}
__device__ __forceinline__ short f2bfs(float f) {
    __hip_bfloat16 h = __float2bfloat16(f);   // RNE
    return *reinterpret_cast<short*>(&h);
}

// ---- LDS layout (bytes) ----
// Hs : [100][256] bf16, row stride 512B, XOR swz -> 51200 (reused as f32 out-stage)
// P  : [112][128] bf16, stride 256B, swz         -> 28672
// SS/SD: 112 f32 each                            -> 896
#define HS_OFF 0
#define P_OFF  51200
#define SS_OFF 79872
#define SD_OFF 80320
#define SMEM_BYTES 80768

__device__ __forceinline__ int hs_addr(int row, int col) {
    return HS_OFF + row * 512 + ((col * 2) ^ ((row & 7) << 4));
}
__device__ __forceinline__ int p_addr(int i, int j) {
    return P_OFF + i * 256 + ((j * 2) ^ ((i & 7) << 4));
}
// f32 output staging in Hs region: [100 rows][128 feats]
__device__ __forceinline__ int st_addr(int row, int f) {
    return HS_OFF + row * 512 + ((f * 4) ^ ((row & 7) << 4));
}

struct LayerPtrs {
    const float* w[4];
    const float* bias[4];
};
struct PrepPtrs {
    const float* w[4];
    const float* as_[4];
    const float* ad_[4];
};

// ws[l] = W_l^T a_src_l, wd[l] = W_l^T a_dst_l (batch-independent) -> d_ws bf16
__global__ __launch_bounds__(256) void prep_kernel(PrepPtrs p, unsigned short* wsd) {
    const int l = blockIdx.x;
    const int d = threadIdx.x;
    __shared__ float As[256], Ad[256];
    As[d] = p.as_[l][d];
    Ad[d] = p.ad_[l][d];
    __syncthreads();
    const float* W = p.w[l];
    float s1 = 0.f, s2 = 0.f;
    for (int o = 0; o < 256; ++o) {
        float wv = W[o * 256 + d];
        s1 = fmaf(wv, As[o], s1);
        s2 = fmaf(wv, Ad[o], s2);
    }
    wsd[l * 512 + d]       = (unsigned short)f2bfs(s1);
    wsd[l * 512 + 256 + d] = (unsigned short)f2bfs(s2);
}

// convert the 4 GAT weight matrices to bf16 (row-major, 256x256 each)
__global__ __launch_bounds__(256) void prep_w_kernel(PrepPtrs p, unsigned short* wbf) {
    const int l = blockIdx.x >> 4, seg = blockIdx.x & 15;
    const float* W = p.w[l];
    const int base = seg * 4096;
    for (int i = base + threadIdx.x; i < base + 4096; i += 256)
        wbf[l * 65536 + i] = (unsigned short)f2bfs(W[i]);
}

__global__ __launch_bounds__(512, 4) void geom_kernel(
    const float* __restrict__ x,        // [B,100,6]
    const float* __restrict__ remap_w,  // [256,6]
    const float* __restrict__ remap_b,  // [256]
    LayerPtrs lp,
    const unsigned short* __restrict__ wsd,   // prep scores (bf16)
    const unsigned short* __restrict__ wbf,   // prep bf16 W (may be null)
    float* __restrict__ out)            // [B,100,256]
{
    extern __shared__ char smem[];
    const int tid  = threadIdx.x;
    const int lane = tid & 63;
    const int wv   = tid >> 6;    // 0..7
    const int c    = lane & 15;
    const int q    = lane >> 4;   // 0..3
    const int b    = blockIdx.x;

    // --- remap: h = relu(x @ remap_w^T + remap_b) ---
    {
        const int o = tid & 255, half = tid >> 8;
        float rw[6];
#pragma unroll
        for (int i = 0; i < 6; ++i) rw[i] = remap_w[o * 6 + i];
        const float rb = remap_b[o];
        const float* xb = x + (size_t)b * 600;
        for (int n = half * 50; n < half * 50 + 50; ++n) {
            float v = rb;
#pragma unroll
            for (int i = 0; i < 6; ++i) v = fmaf(xb[n * 6 + i], rw[i], v);
            v = fmaxf(v, 0.f);
            *(unsigned short*)(smem + hs_addr(n, o)) = (unsigned short)f2bfs(v);
        }
    }

    for (int l = 0; l < 4; ++l) {
        __syncthreads();   // Hs ready; P/scores free

        // g values for this wave's 2 feature tiles, packed bf16x4 as 2 dwords:
        // apack[t][mt] holds g[node mt*16+q*4+j][feat (2wv+t)*16+c], j=0..3
        int apack[2][7][2];

        // ---------- phase A: g = h @ W^T (per-tile, sequential) ----------
#pragma unroll
        for (int t = 0; t < 2; ++t) {
            const int ftile = 2 * wv + t;
            bf16x8 wf[8];
            if (wbf) {
                const unsigned short* wp = wbf + l * 65536 + (ftile * 16 + c) * 256 + q * 8;
#pragma unroll
                for (int kk = 0; kk < 8; ++kk) wf[kk] = *(const bf16x8*)(wp + kk * 32);
            } else {
                const float* wp = lp.w[l] + (ftile * 16 + c) * 256 + q * 8;
#pragma unroll
                for (int kk = 0; kk < 8; ++kk) {
                    f32x4 lo = *(const f32x4*)(wp + kk * 32);
                    f32x4 hi = *(const f32x4*)(wp + kk * 32 + 4);
                    bf16x8 w0;
#pragma unroll
                    for (int j = 0; j < 4; ++j) {
                        w0[j]     = f2bfs(lo[j]);
                        w0[4 + j] = f2bfs(hi[j]);
                    }
                    wf[kk] = w0;
                }
            }
#pragma unroll
            for (int mt = 0; mt < 7; ++mt) {
                int r = mt * 16 + c;
                if (r > 99) r = 99;   // clamped tail (finite garbage; masked by P=0)
                f32x4 ae = {0,0,0,0}, ao = {0,0,0,0};
#pragma unroll
                for (int kk = 0; kk < 8; kk += 2) {
                    bf16x8 afe = *(const bf16x8*)(smem + hs_addr(r, kk * 32 + q * 8));
                    bf16x8 afo = *(const bf16x8*)(smem + hs_addr(r, (kk + 1) * 32 + q * 8));
                    ae = __builtin_amdgcn_mfma_f32_16x16x32_bf16(afe, wf[kk],     ae, 0, 0, 0);
                    ao = __builtin_amdgcn_mfma_f32_16x16x32_bf16(afo, wf[kk + 1], ao, 0, 0, 0);
                }
                f32x4 a = ae + ao;
                bf16x4 g;
#pragma unroll
                for (int j = 0; j < 4; ++j) g[j] = f2bfs(a[j]);
                const int2 gi = *reinterpret_cast<const int2*>(&g);
                apack[t][mt][0] = gi.x;
                apack[t][mt][1] = gi.y;
            }
        }
        // ---------- scores S = h @ [ws, wd] (waves 0..6, tile wv) ----------
        if (wv < 7) {
            int r = wv * 16 + c;
            if (r > 99) r = 99;
            const unsigned short* wsp = wsd + l * 512 + q * 8;
            const unsigned short* wdp = wsp + 256;
            f32x4 sa = {0,0,0,0};
#pragma unroll
            for (int kk = 0; kk < 8; ++kk) {
                bf16x8 af = *(const bf16x8*)(smem + hs_addr(r, kk * 32 + q * 8));
                bf16x8 bs = *(const bf16x8*)(wsp + kk * 32);
                bf16x8 bd = *(const bf16x8*)(wdp + kk * 32);
                bf16x8 bz = {0,0,0,0,0,0,0,0};
                bf16x8 bb = (c == 0) ? bs : ((c == 1) ? bd : bz);
                sa = __builtin_amdgcn_mfma_f32_16x16x32_bf16(af, bb, sa, 0, 0, 0);
            }
            if (c < 2) {
                float* dst = (float*)(smem + (c == 0 ? SS_OFF : SD_OFF));
#pragma unroll
                for (int j = 0; j < 4; ++j) dst[wv * 16 + q * 4 + j] = sa[j];
            }
        }
        __syncthreads();   // SS/SD ready; P free

        // ---------- softmax over sources j per target i (4 lanes/row) ----------
        {
            const int i = tid >> 2, sq = tid & 3;
            if (i < 112) {
                const float sd = ((float*)(smem + SD_OFF))[i];
                const float* Ssf = (const float*)(smem + SS_OFF);
                float vals[4][8];
                float mx = -1e30f;
#pragma unroll
                for (int t = 0; t < 4; ++t) {
                    const int blk = t * 4 + sq;
#pragma unroll
                    for (int e = 0; e < 8; ++e) {
                        const int j = blk * 8 + e;
                        float v;
                        if (j < 100) {
                            float z = sd + Ssf[j];
                            v = (z > 0.f) ? z : 0.2f * z;   // leaky_relu 0.2
                        } else {
                            v = -1e30f;                      // pad -> exp 0
                        }
                        vals[t][e] = v;
                        mx = fmaxf(mx, v);
                    }
                }
                mx = fmaxf(mx, __shfl_xor(mx, 1, 4));
                mx = fmaxf(mx, __shfl_xor(mx, 2, 4));
                float sum = 0.f;
#pragma unroll
                for (int t = 0; t < 4; ++t)
#pragma unroll
                    for (int e = 0; e < 8; ++e) {
                        float ev = __expf(vals[t][e] - mx);
                        vals[t][e] = ev;
                        sum += ev;
                    }
                sum += __shfl_xor(sum, 1, 4);
                sum += __shfl_xor(sum, 2, 4);
                const float inv = 1.f / sum;
#pragma unroll
                for (int t = 0; t < 4; ++t) {
                    const int blk = t * 4 + sq;
                    bf16x8 pv;
#pragma unroll
                    for (int e = 0; e < 8; ++e) pv[e] = f2bfs(vals[t][e] * inv);
                    *(bf16x8*)(smem + p_addr(i, blk * 8)) = pv;
                }
            }
        }
        __syncthreads();   // P ready

        // ---------- PV: out = attn @ g (+bias, +residual, relu) ----------
        {
            // Build B-fragments from apack via lane permute:
            // gf[t][ks][e] = g[node ks*32+q*8+e][feat (2wv+t)*16+c]
            //   source lane q' = (2q + (e>>2)) & 3 (same c), source mt' = 2ks + (q>>1)
            bf16x8 gft[2][4];
#pragma unroll
            for (int t = 0; t < 2; ++t) {
#pragma unroll
                for (int ks = 0; ks < 4; ++ks) {
                    const int m0 = 2 * ks, m1 = 2 * ks + 1;
                    int d[4];
#pragma unroll
                    for (int h = 0; h < 2; ++h) {
                        const int srcl = ((((2 * q + h) & 3) << 4) + c) << 2;
                        const int a0 = __builtin_amdgcn_ds_bpermute(srcl, apack[t][m0][0]);
                        const int a1 = __builtin_amdgcn_ds_bpermute(srcl, apack[t][m0][1]);
                        int b0 = 0, b1 = 0;
                        if (m1 < 7) {   // nodes >= 112 don't exist -> zero (P=0 there)
                            b0 = __builtin_amdgcn_ds_bpermute(srcl, apack[t][m1][0]);
                            b1 = __builtin_amdgcn_ds_bpermute(srcl, apack[t][m1][1]);
                        }
                        const bool hi = (q & 2);
                        d[h * 2 + 0] = hi ? b0 : a0;
                        d[h * 2 + 1] = hi ? b1 : a1;
                    }
                    i32x4 gi = {d[0], d[1], d[2], d[3]};
                    gft[t][ks] = *reinterpret_cast<bf16x8*>(&gi);
                }
            }

            const float bia0 = lp.bias[l][(2 * wv) * 16 + c];
            const float bia1 = lp.bias[l][(2 * wv + 1) * 16 + c];
            float afull[2][7][4];   // only written/read when l==3
#pragma unroll
            for (int mt = 0; mt < 7; ++mt) {
                bf16x8 pf[4];
#pragma unroll
                for (int ks = 0; ks < 4; ++ks)
                    pf[ks] = *(const bf16x8*)(smem + p_addr(mt * 16 + c, ks * 32 + q * 8));
                f32x4 e0 = {0,0,0,0}, o0 = {0,0,0,0}, e1 = {0,0,0,0}, o1 = {0,0,0,0};
#pragma unroll
                for (int ks = 0; ks < 4; ks += 2) {
                    e0 = __builtin_amdgcn_mfma_f32_16x16x32_bf16(pf[ks],     gft[0][ks],     e0, 0, 0, 0);
                    o0 = __builtin_amdgcn_mfma_f32_16x16x32_bf16(pf[ks + 1], gft[0][ks + 1], o0, 0, 0, 0);
                    e1 = __builtin_amdgcn_mfma_f32_16x16x32_bf16(pf[ks],     gft[1][ks],     e1, 0, 0, 0);
                    o1 = __builtin_amdgcn_mfma_f32_16x16x32_bf16(pf[ks + 1], gft[1][ks + 1], o1, 0, 0, 0);
                }
                f32x4 a0 = e0 + o0, a1 = e1 + o1;
                const int row = mt * 16 + q * 4;
                if (l < 3) {
#pragma unroll
                    for (int j = 0; j < 4; ++j) {
                        if (row + j < 100) {
                            {
                                const int ad = hs_addr(row + j, (2 * wv) * 16 + c);
                                float r = bf2f(*(unsigned short*)(smem + ad));
                                *(unsigned short*)(smem + ad) =
                                    (unsigned short)f2bfs(fmaxf(a0[j] + bia0 + r, 0.f));
                            }
                            {
                                const int ad = hs_addr(row + j, (2 * wv + 1) * 16 + c);
                                float r = bf2f(*(unsigned short*)(smem + ad));
                                *(unsigned short*)(smem + ad) =
                                    (unsigned short)f2bfs(fmaxf(a1[j] + bia1 + r, 0.f));
                            }
                        }
                    }
                } else {
#pragma unroll
                    for (int j = 0; j < 4; ++j) {
                        afull[0][mt][j] = a0[j] + bia0;
                        afull[1][mt][j] = a1[j] + bia1;
                    }
                }
            }

            if (l == 3) {
                // stage f32 into Hs region (dead now) and copy with full-line coalescing
                float* ob = out + (size_t)b * 25600;
#pragma unroll
                for (int half = 0; half < 2; ++half) {
                    if ((wv >> 2) == half) {
#pragma unroll
                        for (int t = 0; t < 2; ++t) {
                            const int fs = (2 * wv + t) * 16 + c - half * 128;  // 0..127
#pragma unroll
                            for (int mt = 0; mt < 7; ++mt) {
                                const int row = mt * 16 + q * 4;
#pragma unroll
                                for (int j = 0; j < 4; ++j) {
                                    if (row + j < 100)
                                        *(float*)(smem + st_addr(row + j, fs)) = afull[t][mt][j];
                                }
                            }
                        }
                    }
                    __syncthreads();   // stage ready
                    for (int cidx = tid; cidx < 3200; cidx += 512) {
                        const int row = cidx >> 5, fb = cidx & 31;
                        f32x4 v = *(const f32x4*)(smem + st_addr(row, fb * 4));
                        *(f32x4*)(ob + row * 256 + half * 128 + fb * 4) = v;
                    }
                    __syncthreads();   // before next half overwrites stage
                }
            }
        }
    }
}

extern "C" void kernel_launch(void* const* d_in, const int* in_sizes, int n_in,
                              void* d_out, int out_size, void* d_ws, size_t ws_size,
                              hipStream_t stream) {
    const float* x       = (const float*)d_in[0];
    const float* remap_w = (const float*)d_in[2];
    const float* remap_b = (const float*)d_in[3];
    PrepPtrs pp;
    LayerPtrs lp;
    for (int l = 0; l < 4; ++l) {
        lp.w[l]    = pp.w[l]   = (const float*)d_in[4 + 4 * l];
        pp.as_[l]  = (const float*)d_in[5 + 4 * l];
        pp.ad_[l]  = (const float*)d_in[6 + 4 * l];
        lp.bias[l] = (const float*)d_in[7 + 4 * l];
    }
    unsigned short* wsd = (unsigned short*)d_ws;
    // bf16 weight cache right after wsd (4 KB): 4 x 256 x 256 bf16 = 512 KB
    unsigned short* wbf = nullptr;
    if (ws_size >= (size_t)(4096 + 4 * 65536 * 2)) {
        wbf = (unsigned short*)((char*)d_ws + 4096);
    }

    prep_kernel<<<4, 256, 0, stream>>>(pp, wsd);
    if (wbf) prep_w_kernel<<<64, 256, 0, stream>>>(pp, wbf);

    (void)hipFuncSetAttribute(reinterpret_cast<const void*>(geom_kernel),
                              hipFuncAttributeMaxDynamicSharedMemorySize, SMEM_BYTES);
    geom_kernel<<<2048, 512, SMEM_BYTES, stream>>>(x, remap_w, remap_b, lp, wsd, wbf,
                                                   (float*)d_out);
}

// Round 6
// 654.092 us; speedup vs baseline: 2.2700x; 2.2700x over previous
//
#include <hip/hip_runtime.h>
#include <hip/hip_bf16.h>

// GeomEncoder: B=2048, N=100 nodes, D=256, 4 dense-GAT layers.
// 1024 threads (16 waves) per batch-block, 1 block/CU, 4 waves/SIMD.
// Register-dieted to fit the 64-arch-VGPR half of the unified file (no spill):
//  - phase A K-split (wf[4] not wf[8]); acc[7] lives in AGPR half
//  - bf16 residual re-read from Hs (no res[] regs)
//  - final layer writes through to an LDS f32 stage (no afull[] regs)

typedef __attribute__((ext_vector_type(8))) short bf16x8;  // 8 bf16 = 4 VGPRs
typedef __attribute__((ext_vector_type(4))) short bf16x4;  // 8 bytes
typedef __attribute__((ext_vector_type(4))) float f32x4;

__device__ __forceinline__ float bf2f(unsigned short u) {
    return __uint_as_float(((unsigned)u) << 16);
}
__device__ __forceinline__ short f2bfs(float f) {
    __hip_bfloat16 h = __float2bfloat16(f);   // RNE
    return *reinterpret_cast<short*>(&h);
}

// ---- LDS layout (bytes) ----
// Hs : [100][256] bf16, row stride 512B, XOR swz   -> 51200
// GsT: [256 feat][128 node] bf16, stride 256B, swz -> 65536
// P  : [112][128] bf16, stride 256B, swz           -> 28672
// SS/SD: 112 f32 each
// final-layer f32 stage [100][1024B] overlaps Hs+GsT (both dead then)
#define HS_OFF 0
#define GT_OFF 51200
#define P_OFF  116736
#define SS_OFF 145408
#define SD_OFF 145856
#define SMEM_BYTES 146304

__device__ __forceinline__ int hs_addr(int row, int col) {
    return HS_OFF + row * 512 + ((col * 2) ^ ((row & 7) << 4));
}
__device__ __forceinline__ int gt_addr(int o, int n) {
    return GT_OFF + o * 256 + ((n * 2) ^ ((o & 7) << 4));
}
__device__ __forceinline__ int p_addr(int i, int j) {
    return P_OFF + i * 256 + ((j * 2) ^ ((i & 7) << 4));
}
// f32 output stage: [100 rows][256 f32], row stride 1024B
__device__ __forceinline__ int st_addr(int row, int f) {
    return row * 1024 + ((f * 4) ^ ((row & 7) << 4));
}

struct LayerPtrs {
    const float* w[4];
    const float* bias[4];
};
struct PrepPtrs {
    const float* w[4];
    const float* as_[4];
    const float* ad_[4];
};

// ws[l] = W_l^T a_src_l, wd[l] = W_l^T a_dst_l (batch-independent) -> d_ws bf16
__global__ __launch_bounds__(256) void prep_kernel(PrepPtrs p, unsigned short* wsd) {
    const int l = blockIdx.x;
    const int d = threadIdx.x;
    __shared__ float As[256], Ad[256];
    As[d] = p.as_[l][d];
    Ad[d] = p.ad_[l][d];
    __syncthreads();
    const float* W = p.w[l];
    float s1 = 0.f, s2 = 0.f;
    for (int o = 0; o < 256; ++o) {
        float wv = W[o * 256 + d];
        s1 = fmaf(wv, As[o], s1);
        s2 = fmaf(wv, Ad[o], s2);
    }
    wsd[l * 512 + d]       = (unsigned short)f2bfs(s1);
    wsd[l * 512 + 256 + d] = (unsigned short)f2bfs(s2);
}

// convert the 4 GAT weight matrices to bf16 (row-major, 256x256 each)
__global__ __launch_bounds__(256) void prep_w_kernel(PrepPtrs p, unsigned short* wbf) {
    const int l = blockIdx.x >> 4, seg = blockIdx.x & 15;
    const float* W = p.w[l];
    const int base = seg * 4096;
    for (int i = base + threadIdx.x; i < base + 4096; i += 256)
        wbf[l * 65536 + i] = (unsigned short)f2bfs(W[i]);
}

__global__ __launch_bounds__(1024) void geom_kernel(
    const float* __restrict__ x,        // [B,100,6]
    const float* __restrict__ remap_w,  // [256,6]
    const float* __restrict__ remap_b,  // [256]
    LayerPtrs lp,
    const unsigned short* __restrict__ wsd,   // prep scores (bf16)
    const unsigned short* __restrict__ wbf,   // prep bf16 W (may be null)
    float* __restrict__ out)            // [B,100,256]
{
    extern __shared__ char smem[];
    const int tid  = threadIdx.x;
    const int lane = tid & 63;
    const int wv   = tid >> 6;    // 0..15
    const int c    = lane & 15;
    const int q    = lane >> 4;   // 0..3
    const int b    = blockIdx.x;
    const int ft   = wv;          // feature tile owned by this wave

    // --- zero entire GsT region once (pad node cols 112..127 stay zero) ---
    for (int off = tid * 16; off < 65536; off += 1024 * 16) {
        *(f32x4*)(smem + GT_OFF + off) = f32x4{0.f, 0.f, 0.f, 0.f};
    }

    // --- remap: h = relu(x @ remap_w^T + remap_b) ---
    {
        const int o = tid & 255, quarter = tid >> 8;
        float rw[6];
#pragma unroll
        for (int i = 0; i < 6; ++i) rw[i] = remap_w[o * 6 + i];
        const float rb = remap_b[o];
        const float* xb = x + (size_t)b * 600;
        for (int n = quarter * 25; n < quarter * 25 + 25; ++n) {
            float v = rb;
#pragma unroll
            for (int i = 0; i < 6; ++i) v = fmaf(xb[n * 6 + i], rw[i], v);
            v = fmaxf(v, 0.f);
            *(unsigned short*)(smem + hs_addr(n, o)) = (unsigned short)f2bfs(v);
        }
    }

    for (int l = 0; l < 4; ++l) {
        __syncthreads();   // Hs ready; GsT/P/scores free

        // ---------- phase A: g = h @ W^T -> GsT, K-split to halve wf regs ----------
        {
            f32x4 acc[7];
#pragma unroll
            for (int mt = 0; mt < 7; ++mt) acc[mt] = f32x4{0.f, 0.f, 0.f, 0.f};
#pragma unroll
            for (int half = 0; half < 2; ++half) {
                bf16x8 wf[4];
                if (wbf) {
                    const unsigned short* wp =
                        wbf + l * 65536 + (ft * 16 + c) * 256 + half * 128 + q * 8;
#pragma unroll
                    for (int kk = 0; kk < 4; ++kk) wf[kk] = *(const bf16x8*)(wp + kk * 32);
                } else {
                    const float* wp = lp.w[l] + (ft * 16 + c) * 256 + half * 128 + q * 8;
#pragma unroll
                    for (int kk = 0; kk < 4; ++kk) {
                        f32x4 lo = *(const f32x4*)(wp + kk * 32);
                        f32x4 hi = *(const f32x4*)(wp + kk * 32 + 4);
                        bf16x8 w0;
#pragma unroll
                        for (int j = 0; j < 4; ++j) {
                            w0[j]     = f2bfs(lo[j]);
                            w0[4 + j] = f2bfs(hi[j]);
                        }
                        wf[kk] = w0;
                    }
                }
#pragma unroll
                for (int mt = 0; mt < 7; ++mt) {
                    int r = mt * 16 + c;
                    if (r > 99) r = 99;   // clamped tail (finite; masked downstream)
#pragma unroll
                    for (int kk = 0; kk < 4; ++kk) {
                        bf16x8 af = *(const bf16x8*)(
                            smem + hs_addr(r, half * 128 + kk * 32 + q * 8));
                        acc[mt] = __builtin_amdgcn_mfma_f32_16x16x32_bf16(af, wf[kk],
                                                                          acc[mt], 0, 0, 0);
                    }
                }
            }
#pragma unroll
            for (int mt = 0; mt < 7; ++mt) {
                bf16x4 g;
#pragma unroll
                for (int j = 0; j < 4; ++j) g[j] = f2bfs(acc[mt][j]);
                // D row = node mt*16+q*4+j, D col = feat ft*16+c -> GsT[feat][node]
                *(bf16x4*)(smem + gt_addr(ft * 16 + c, mt * 16 + q * 4)) = g;
            }
        }
        // ---------- scores S = h @ [ws, wd] (waves 9..15, tile wv-9) ----------
        if (wv >= 9) {
            const int st = wv - 9;
            int r = st * 16 + c;
            if (r > 99) r = 99;
            const unsigned short* wsp = wsd + l * 512 + q * 8;
            const unsigned short* wdp = wsp + 256;
            f32x4 sa = {0,0,0,0};
#pragma unroll
            for (int kk = 0; kk < 8; ++kk) {
                bf16x8 af = *(const bf16x8*)(smem + hs_addr(r, kk * 32 + q * 8));
                bf16x8 bs = *(const bf16x8*)(wsp + kk * 32);
                bf16x8 bd = *(const bf16x8*)(wdp + kk * 32);
                bf16x8 bz = {0,0,0,0,0,0,0,0};
                bf16x8 bb = (c == 0) ? bs : ((c == 1) ? bd : bz);
                sa = __builtin_amdgcn_mfma_f32_16x16x32_bf16(af, bb, sa, 0, 0, 0);
            }
            if (c < 2) {
                float* dst = (float*)(smem + (c == 0 ? SS_OFF : SD_OFF));
#pragma unroll
                for (int j = 0; j < 4; ++j) dst[st * 16 + q * 4 + j] = sa[j];
            }
        }
        __syncthreads();   // GsT, SS/SD ready

        // ---------- softmax over sources j per target i (8 lanes per row) ----------
        {
            const int i = tid >> 3, s3 = tid & 7;
            if (i < 112) {
                const float sd = ((float*)(smem + SD_OFF))[i];
                const float* Ssf = (const float*)(smem + SS_OFF);
                float vals[2][8];
                float mx = -1e30f;
#pragma unroll
                for (int t = 0; t < 2; ++t) {
                    const int blk = t * 8 + s3;
#pragma unroll
                    for (int e = 0; e < 8; ++e) {
                        const int j = blk * 8 + e;
                        float v;
                        if (j < 100) {
                            float z = sd + Ssf[j];
                            v = (z > 0.f) ? z : 0.2f * z;   // leaky_relu 0.2
                        } else {
                            v = -1e30f;                      // pad -> exp 0
                        }
                        vals[t][e] = v;
                        mx = fmaxf(mx, v);
                    }
                }
                mx = fmaxf(mx, __shfl_xor(mx, 1, 8));
                mx = fmaxf(mx, __shfl_xor(mx, 2, 8));
                mx = fmaxf(mx, __shfl_xor(mx, 4, 8));
                float sum = 0.f;
#pragma unroll
                for (int t = 0; t < 2; ++t)
#pragma unroll
                    for (int e = 0; e < 8; ++e) {
                        float ev = __expf(vals[t][e] - mx);
                        vals[t][e] = ev;
                        sum += ev;
                    }
                sum += __shfl_xor(sum, 1, 8);
                sum += __shfl_xor(sum, 2, 8);
                sum += __shfl_xor(sum, 4, 8);
                const float inv = 1.f / sum;
#pragma unroll
                for (int t = 0; t < 2; ++t) {
                    const int blk = t * 8 + s3;
                    bf16x8 pv;
#pragma unroll
                    for (int e = 0; e < 8; ++e) pv[e] = f2bfs(vals[t][e] * inv);
                    *(bf16x8*)(smem + p_addr(i, blk * 8)) = pv;
                }
            }
        }
        __syncthreads();   // P ready

        // ---------- PV: out = attn @ g (+bias, +residual, relu) ----------
        {
            const float b0 = lp.bias[l][ft * 16 + c];
            bf16x8 gf[4];
#pragma unroll
            for (int ks = 0; ks < 4; ++ks)
                gf[ks] = *(const bf16x8*)(smem + gt_addr(ft * 16 + c, ks * 32 + q * 8));

            if (l == 3) __syncthreads();   // all gf loaded before stage overwrites Hs+GsT

#pragma unroll
            for (int mt = 0; mt < 7; ++mt) {
                f32x4 ae = {0,0,0,0}, ao = {0,0,0,0};
#pragma unroll
                for (int ks = 0; ks < 4; ks += 2) {
                    bf16x8 pe = *(const bf16x8*)(smem + p_addr(mt * 16 + c, ks * 32 + q * 8));
                    bf16x8 po = *(const bf16x8*)(smem + p_addr(mt * 16 + c, (ks + 1) * 32 + q * 8));
                    ae = __builtin_amdgcn_mfma_f32_16x16x32_bf16(pe, gf[ks],     ae, 0, 0, 0);
                    ao = __builtin_amdgcn_mfma_f32_16x16x32_bf16(po, gf[ks + 1], ao, 0, 0, 0);
                }
                f32x4 a = ae + ao;
                const int row = mt * 16 + q * 4;
                if (l < 3) {
#pragma unroll
                    for (int j = 0; j < 4; ++j) {
                        if (row + j < 100) {
                            const int ad = hs_addr(row + j, ft * 16 + c);
                            float r = bf2f(*(unsigned short*)(smem + ad));
                            float v = fmaxf(a[j] + b0 + r, 0.f);
                            *(unsigned short*)(smem + ad) = (unsigned short)f2bfs(v);
                        }
                    }
                } else {
                    // write-through to f32 stage (Hs+GsT region, both dead now)
#pragma unroll
                    for (int j = 0; j < 4; ++j) {
                        if (row + j < 100)
                            *(float*)(smem + st_addr(row + j, ft * 16 + c)) = a[j] + b0;
                    }
                }
            }

            if (l == 3) {
                __syncthreads();   // stage complete
                float* ob = out + (size_t)b * 25600;
                for (int cidx = tid; cidx < 6400; cidx += 1024) {
                    const int row = cidx >> 6, fb = cidx & 63;
                    f32x4 v = *(const f32x4*)(smem + st_addr(row, fb * 4));
                    *(f32x4*)(ob + row * 256 + fb * 4) = v;
                }
            }
        }
    }
}

extern "C" void kernel_launch(void* const* d_in, const int* in_sizes, int n_in,
                              void* d_out, int out_size, void* d_ws, size_t ws_size,
                              hipStream_t stream) {
    const float* x       = (const float*)d_in[0];
    const float* remap_w = (const float*)d_in[2];
    const float* remap_b = (const float*)d_in[3];
    PrepPtrs pp;
    LayerPtrs lp;
    for (int l = 0; l < 4; ++l) {
        lp.w[l]    = pp.w[l]   = (const float*)d_in[4 + 4 * l];
        pp.as_[l]  = (const float*)d_in[5 + 4 * l];
        pp.ad_[l]  = (const float*)d_in[6 + 4 * l];
        lp.bias[l] = (const float*)d_in[7 + 4 * l];
    }
    unsigned short* wsd = (unsigned short*)d_ws;
    // bf16 weight cache right after wsd (4 KB): 4 x 256 x 256 bf16 = 512 KB
    unsigned short* wbf = nullptr;
    if (ws_size >= (size_t)(4096 + 4 * 65536 * 2)) {
        wbf = (unsigned short*)((char*)d_ws + 4096);
    }

    prep_kernel<<<4, 256, 0, stream>>>(pp, wsd);
    if (wbf) prep_w_kernel<<<64, 256, 0, stream>>>(pp, wbf);

    (void)hipFuncSetAttribute(reinterpret_cast<const void*>(geom_kernel),
                              hipFuncAttributeMaxDynamicSharedMemorySize, SMEM_BYTES);
    geom_kernel<<<2048, 1024, SMEM_BYTES, stream>>>(x, remap_w, remap_b, lp, wsd, wbf,
                                                    (float*)d_out);
}